// Round 9
// baseline (448.913 us; speedup 1.0000x reference)
//
#include <hip/hip_runtime.h>
#include <math.h>

#define D_DIM 512

typedef short short8v __attribute__((ext_vector_type(8)));
typedef float f32x16 __attribute__((ext_vector_type(16)));

__device__ inline unsigned short f2bf(float f) {
    union { float f; unsigned int u; } a; a.f = f;
    unsigned int u = a.u;
    unsigned int r = (u + 0x7fffu + ((u >> 16) & 1u)) >> 16;  // RNE
    return (unsigned short)r;
}

// pack 2 fp32 -> packed bf16x2 (round-to-nearest, ties up): 3 VALU ops
__device__ inline unsigned int pk2bf(float lo, float hi) {
    union { float f; unsigned int u; } A, B;
    A.f = lo; B.f = hi;
    return __builtin_amdgcn_perm(B.u + 0x8000u, A.u + 0x8000u, 0x07060302u);
}

__device__ inline short8v cvt8(float4 a, float4 b) {
    union { unsigned int i[4]; short8v s; } o;
    o.i[0] = pk2bf(a.x, a.y);
    o.i[1] = pk2bf(a.z, a.w);
    o.i[2] = pk2bf(b.x, b.y);
    o.i[3] = pk2bf(b.z, b.w);
    return o.s;
}

// fast tanh: 1 - 2/(e^{2y}+1); saturates correctly at +-1
__device__ inline float fast_tanh(float y) {
    float e2 = __expf(2.f * y);
    return 1.f - __fdividef(2.f, e2 + 1.f);
}

// ---------------------------------------------------------------------------
// wt: W[k][e] fp32 -> Wb2 col-tile-major bf16.
// Wb2 ushort index: ct*16384 + ((k>>4)*2 + ((k>>3)&1))*256 + (e&31)*8 + (k&7)
// where ct = e>>5.  A wave's B-slice (one ct) is 32 KB contiguous; per k-step
// load (half*32+nl)*8 + ks*512 is a coalesced 1 KB wave read.
// ---------------------------------------------------------------------------
__global__ __launch_bounds__(256) void wt_kernel(const float* __restrict__ W,
                                                 unsigned short* __restrict__ Wb2) {
    __shared__ __align__(16) unsigned short lbuf[16384];
    const int ct = blockIdx.x;          // 0..15
    const int tid = threadIdx.x;
    #pragma unroll
    for (int i = 0; i < 2; ++i) {
        int k = tid * 2 + i;            // 0..511
        const float* wr = W + (size_t)k * D_DIM + ct * 32;
        int kk = (k >> 4) * 2 + ((k >> 3) & 1);   // 0..63
        int kj = k & 7;
        #pragma unroll
        for (int q = 0; q < 8; ++q) {
            float4 v = *(const float4*)(wr + q * 4);
            int e0 = q * 4;
            lbuf[(kk * 32 + e0 + 0) * 8 + kj] = f2bf(v.x);
            lbuf[(kk * 32 + e0 + 1) * 8 + kj] = f2bf(v.y);
            lbuf[(kk * 32 + e0 + 2) * 8 + kj] = f2bf(v.z);
            lbuf[(kk * 32 + e0 + 3) * 8 + kj] = f2bf(v.w);
        }
    }
    __syncthreads();
    #pragma unroll
    for (int i = 0; i < 8; ++i) {
        int c = tid + i * 256;
        *(short8v*)(Wb2 + (size_t)ct * 16384 + c * 8) = *(const short8v*)&lbuf[c * 8];
    }
}

// ---------------------------------------------------------------------------
// Barrier-free MFMA GEMM + fused tanh/dot-u epilogue.
// 512 thr = 8 waves; block = col-half ch (8 col-tiles of 32) x m-group of
// 8 chunks x 64 rows. B entirely in registers (32 x short8v = 128 VGPR,
// loaded once). A loaded straight from global x, 2-deep pipelined, converted
// in-register. NO LDS and NO barriers in the K-loop.
// ait2: [2][M] partials (one slot per col-half), summed by softmax.
// ---------------------------------------------------------------------------
__global__ __launch_bounds__(512, 2) void gemm_ait_mfma(
    const float* __restrict__ x, const unsigned short* __restrict__ Wb2,
    const float* __restrict__ bias, const float* __restrict__ u,
    float* __restrict__ ait2, int Mtot, int mtiles)
{
    __shared__ float rowpart[8][64];

    const int tid  = threadIdx.x;
    const int wave = tid >> 6;        // 0..7 -> col tile within half
    const int lane = tid & 63;
    const int half = lane >> 5;
    const int nl   = lane & 31;
    const int ch   = blockIdx.x & 1;  // col half
    const int mg   = blockIdx.x >> 1; // m group
    const int ct   = ch * 8 + wave;
    const int col  = ct * 32 + nl;

    // B-slice into registers: 32 k-steps x 16B/lane
    short8v breg[32];
    {
        const unsigned short* wp = Wb2 + (size_t)ct * 16384 + (half * 32 + nl) * 8;
        #pragma unroll
        for (int ks = 0; ks < 32; ++ks)
            breg[ks] = *(const short8v*)(wp + ks * 512);
    }
    const float be = bias[col];
    const float ue = u[col];

    for (int i = 0; i < mtiles; ++i) {
        const int m0 = (mg * mtiles + i) * 64;
        const float* xr0 = x + (size_t)(m0 + nl) * D_DIM + half * 8;
        const float* xr1 = xr0 + (size_t)32 * D_DIM;

        f32x16 acc0, acc1;
        #pragma unroll
        for (int r = 0; r < 16; ++r) { acc0[r] = 0.f; acc1[r] = 0.f; }

        // 2-deep A pipeline
        float4 a0[2][2], a1[2][2];
        #pragma unroll
        for (int s = 0; s < 2; ++s) {
            a0[s][0] = *(const float4*)(xr0 + s * 16);
            a0[s][1] = *(const float4*)(xr0 + s * 16 + 4);
            a1[s][0] = *(const float4*)(xr1 + s * 16);
            a1[s][1] = *(const float4*)(xr1 + s * 16 + 4);
        }

        #pragma unroll
        for (int ks = 0; ks < 32; ++ks) {
            const int sl = ks & 1;
            short8v af0 = cvt8(a0[sl][0], a0[sl][1]);
            short8v af1 = cvt8(a1[sl][0], a1[sl][1]);
            if (ks + 2 < 32) {
                a0[sl][0] = *(const float4*)(xr0 + (ks + 2) * 16);
                a0[sl][1] = *(const float4*)(xr0 + (ks + 2) * 16 + 4);
                a1[sl][0] = *(const float4*)(xr1 + (ks + 2) * 16);
                a1[sl][1] = *(const float4*)(xr1 + (ks + 2) * 16 + 4);
            }
            acc0 = __builtin_amdgcn_mfma_f32_32x32x16_bf16(af0, breg[ks], acc0, 0, 0, 0);
            acc1 = __builtin_amdgcn_mfma_f32_32x32x16_bf16(af1, breg[ks], acc1, 0, 0, 0);
        }

        // epilogue: partial ait over this col-slice
        // C/D layout: col = nl, row = (r&3) + 8*(r>>2) + 4*half  (+32 for acc1)
        float rs0[16], rs1[16];
        #pragma unroll
        for (int r = 0; r < 16; ++r) {
            rs0[r] = fast_tanh(acc0[r] + be) * ue;
            rs1[r] = fast_tanh(acc1[r] + be) * ue;
        }
        #pragma unroll
        for (int r = 0; r < 16; ++r) {
            float v0 = rs0[r], v1 = rs1[r];
            v0 += __shfl_xor(v0, 1, 64);  v1 += __shfl_xor(v1, 1, 64);
            v0 += __shfl_xor(v0, 2, 64);  v1 += __shfl_xor(v1, 2, 64);
            v0 += __shfl_xor(v0, 4, 64);  v1 += __shfl_xor(v1, 4, 64);
            v0 += __shfl_xor(v0, 8, 64);  v1 += __shfl_xor(v1, 8, 64);
            v0 += __shfl_xor(v0, 16, 64); v1 += __shfl_xor(v1, 16, 64);
            rs0[r] = v0; rs1[r] = v1;
        }
        if (nl == 0) {
            #pragma unroll
            for (int r = 0; r < 16; ++r) {
                int row = (r & 3) + 8 * (r >> 2) + 4 * half;
                rowpart[wave][row]      = rs0[r];
                rowpart[wave][row + 32] = rs1[r];
            }
        }
        __syncthreads();
        if (tid < 64) {
            float s = 0.f;
            #pragma unroll
            for (int w = 0; w < 8; ++w) s += rowpart[w][tid];
            ait2[(size_t)ch * Mtot + m0 + tid] = s;
        }
        __syncthreads();
    }
}

// ---- fp32 fallback GEMM (only if ws < 1 MiB — never observed) ----
__global__ __launch_bounds__(256) void gemm_ait_f32(
    const float* __restrict__ x, const float* __restrict__ W,
    const float* __restrict__ bias, const float* __restrict__ u,
    float* __restrict__ ait)
{
    __shared__ float xsf[64][68];
    __shared__ float wshf[64][132];
    const int tid = threadIdx.x;
    const int tx = tid & 15, ty = tid >> 4;
    const int m0 = blockIdx.x * 64;
    float rowsum[4] = {0.f, 0.f, 0.f, 0.f};
    for (int e0 = 0; e0 < D_DIM; e0 += 128) {
        float acc[4][8];
        #pragma unroll
        for (int i = 0; i < 4; ++i)
            #pragma unroll
            for (int j = 0; j < 8; ++j) acc[i][j] = 0.f;
        for (int kc = 0; kc < D_DIM; kc += 64) {
            #pragma unroll
            for (int i = 0; i < 4; ++i) {
                int idx = tid + i * 256;
                int r = idx >> 4, c = (idx & 15) * 4;
                *(float4*)&xsf[r][c] = *(const float4*)(x + (size_t)(m0 + r) * D_DIM + kc + c);
            }
            #pragma unroll
            for (int i = 0; i < 8; ++i) {
                int idx = tid + i * 256;
                int r = idx >> 5, c = (idx & 31) * 4;
                *(float4*)&wshf[r][c] = *(const float4*)(W + (size_t)(kc + r) * D_DIM + e0 + c);
            }
            __syncthreads();
            #pragma unroll 4
            for (int k = 0; k < 64; ++k) {
                float xv[4];
                #pragma unroll
                for (int i = 0; i < 4; ++i) xv[i] = xsf[ty * 4 + i][k];
                float4 w0 = *(const float4*)&wshf[k][tx * 8];
                float4 w1 = *(const float4*)&wshf[k][tx * 8 + 4];
                #pragma unroll
                for (int i = 0; i < 4; ++i) {
                    acc[i][0] += xv[i] * w0.x; acc[i][1] += xv[i] * w0.y;
                    acc[i][2] += xv[i] * w0.z; acc[i][3] += xv[i] * w0.w;
                    acc[i][4] += xv[i] * w1.x; acc[i][5] += xv[i] * w1.y;
                    acc[i][6] += xv[i] * w1.z; acc[i][7] += xv[i] * w1.w;
                }
            }
            __syncthreads();
        }
        #pragma unroll
        for (int j = 0; j < 8; ++j) {
            int e = e0 + tx * 8 + j;
            float be = bias[e], ue = u[e];
            #pragma unroll
            for (int i = 0; i < 4; ++i) rowsum[i] += tanhf(acc[i][j] + be) * ue;
        }
    }
    float* red = &xsf[0][0];
    #pragma unroll
    for (int i = 0; i < 4; ++i) red[(ty * 4 + i) * 16 + tx] = rowsum[i];
    __syncthreads();
    if (tid < 64) {
        float s = 0.f;
        #pragma unroll
        for (int j = 0; j < 16; ++j) s += red[tid * 16 + j];
        ait[m0 + tid] = s;
    }
}

// ---- softmax over T, summing `dual` partial slots, result in slot 0 ----
__global__ __launch_bounds__(256) void softmax_kernel(float* __restrict__ p,
                                                      int Mtot, int T, int dual)
{
    const int b = blockIdx.x;
    float* base = p + (size_t)b * T;
    const float* base2 = p + (size_t)Mtot + (size_t)b * T;
    const int tid = threadIdx.x;
    float ev[8];
    float local = 0.f;
    #pragma unroll
    for (int i = 0; i < 8; ++i) {
        int idx = tid + i * 256;
        float v = base[idx];
        if (dual) v += base2[idx];
        ev[i] = expf(v);
        local += ev[i];
    }
    #pragma unroll
    for (int off = 32; off > 0; off >>= 1)
        local += __shfl_down(local, off, 64);
    __shared__ float wsum[4];
    const int wv = tid >> 6, lane = tid & 63;
    if (lane == 0) wsum[wv] = local;
    __syncthreads();
    float total = wsum[0] + wsum[1] + wsum[2] + wsum[3];
    float inv = 1.0f / (total + 1e-7f);
    #pragma unroll
    for (int i = 0; i < 8; ++i) base[tid + i * 256] = ev[i] * inv;
}

// ---- pooling: 256-t chunk per block, 2 streams, deep unroll ----
__global__ __launch_bounds__(256) void pool_partial_kernel(
    const float* __restrict__ x, const float* __restrict__ a,
    float* __restrict__ partial, int T)
{
    const int chunks = T >> 8;               // 8
    const int b = blockIdx.x / chunks;
    const int c = blockIdx.x % chunks;
    const int tid = threadIdx.x;
    const int th = tid >> 7;
    const int d = (tid & 127) * 4;

    const float* xp = x + ((size_t)b * T + c * 256) * D_DIM + d;
    const float* ap = a + (size_t)b * T + c * 256;

    float4 acc = {0.f, 0.f, 0.f, 0.f};
    #pragma unroll 8
    for (int t = th; t < 256; t += 2) {
        float s = ap[t];
        float4 xv = *(const float4*)(xp + (size_t)t * D_DIM);
        acc.x += xv.x * s; acc.y += xv.y * s;
        acc.z += xv.z * s; acc.w += xv.w * s;
    }
    __shared__ float4 tmp[128];
    if (th == 1) tmp[tid & 127] = acc;
    __syncthreads();
    if (th == 0) {
        float4 o = tmp[tid];
        acc.x += o.x; acc.y += o.y; acc.z += o.z; acc.w += o.w;
        *(float4*)(partial + (size_t)blockIdx.x * D_DIM + tid * 4) = acc;
    }
}

__global__ __launch_bounds__(256) void pool_reduce_kernel(
    const float* __restrict__ partial, float* __restrict__ out, int chunks)
{
    const int b = blockIdx.x;
    const int tid = threadIdx.x;
    const int d = tid * 2;
    float2 acc = {0.f, 0.f};
    for (int c = 0; c < chunks; ++c) {
        float2 v = *(const float2*)(partial + ((size_t)b * chunks + c) * D_DIM + d);
        acc.x += v.x; acc.y += v.y;
    }
    *(float2*)(out + (size_t)b * D_DIM + d) = acc;
}

// ---- fallback pool (tiny-ws path only) ----
__global__ __launch_bounds__(256) void pool_atomic_kernel(
    const float* __restrict__ x, const float* __restrict__ a,
    float* __restrict__ out, int T)
{
    const int chunks = T >> 8;
    const int b = blockIdx.x / chunks;
    const int c = blockIdx.x % chunks;
    const int tid = threadIdx.x;
    const int th = tid >> 7;
    const int d = (tid & 127) * 4;
    const float* xp = x + ((size_t)b * T + c * 256) * D_DIM + d;
    const float* ap = a + (size_t)b * T + c * 256;
    float4 acc = {0.f, 0.f, 0.f, 0.f};
    #pragma unroll 8
    for (int t = th; t < 256; t += 2) {
        float s = ap[t];
        float4 xv = *(const float4*)(xp + (size_t)t * D_DIM);
        acc.x += xv.x * s; acc.y += xv.y * s;
        acc.z += xv.z * s; acc.w += xv.w * s;
    }
    __shared__ float4 tmp[128];
    if (th == 1) tmp[tid & 127] = acc;
    __syncthreads();
    if (th == 0) {
        float4 o = tmp[tid];
        float* op = out + (size_t)b * D_DIM + tid * 4;
        atomicAdd(op + 0, acc.x + o.x);
        atomicAdd(op + 1, acc.y + o.y);
        atomicAdd(op + 2, acc.z + o.z);
        atomicAdd(op + 3, acc.w + o.w);
    }
}

extern "C" void kernel_launch(void* const* d_in, const int* in_sizes, int n_in,
                              void* d_out, int out_size, void* d_ws, size_t ws_size,
                              hipStream_t stream)
{
    const float* x    = (const float*)d_in[0];
    const float* W    = (const float*)d_in[1];
    const float* bias = (const float*)d_in[2];
    const float* u    = (const float*)d_in[3];
    float* out = (float*)d_out;

    const int Dd = in_sizes[2];          // 512
    const int M  = in_sizes[0] / Dd;     // 65536
    const int B  = out_size / Dd;        // 32
    const int T  = M / B;                // 2048
    const int chunks = T >> 8;           // 8

    const size_t wb_bytes   = (size_t)Dd * Dd * sizeof(unsigned short);   // 512 KiB
    const size_t ait2_bytes = 2 * (size_t)M * sizeof(float);              // 512 KiB

    if (ws_size >= wb_bytes + ait2_bytes) {
        // [0, 512K): Wb2 during GEMM, reused as pool partials after.
        // [512K, 1M): ait2 (2 col-half partial slots; softmax sums -> slot 0).
        unsigned short* Wb2 = (unsigned short*)d_ws;
        float* ait2    = (float*)((char*)d_ws + wb_bytes);
        float* partial = (float*)d_ws;

        const int mtiles = 8;                         // 64-row chunks per block
        const int grid = 2 * (M / (64 * mtiles));     // 256

        wt_kernel<<<dim3(16), dim3(256), 0, stream>>>(W, Wb2);
        gemm_ait_mfma<<<dim3(grid), dim3(512), 0, stream>>>(x, Wb2, bias, u, ait2, M, mtiles);
        softmax_kernel<<<dim3(B), dim3(256), 0, stream>>>(ait2, M, T, 1);
        pool_partial_kernel<<<dim3(B * chunks), dim3(256), 0, stream>>>(x, ait2, partial, T);
        pool_reduce_kernel<<<dim3(B), dim3(256), 0, stream>>>(partial, out, chunks);
    } else {
        float* ait = (float*)d_ws;
        gemm_ait_f32<<<dim3(M / 64), dim3(256), 0, stream>>>(x, W, bias, u, ait);
        softmax_kernel<<<dim3(B), dim3(256), 0, stream>>>(ait, M, T, 0);
        hipMemsetAsync(d_out, 0, (size_t)out_size * sizeof(float), stream);
        pool_atomic_kernel<<<dim3(B * chunks), dim3(256), 0, stream>>>(x, ait, out, T);
    }
}